// Round 1
// baseline (179.999 us; speedup 1.0000x reference)
//
#include <hip/hip_runtime.h>
#include <hip/hip_bf16.h>

#define D 128
#define TWO_D 256

typedef __attribute__((ext_vector_type(8))) short short8;
typedef __attribute__((ext_vector_type(4))) float floatx4;

__device__ inline unsigned short f2bf(float f) {
    union { __hip_bfloat16 h; unsigned short s; } u;
    u.h = __float2bfloat16(f);
    return u.s;
}

__device__ inline float bflo(unsigned int w) { return __uint_as_float(w << 16); }
__device__ inline float bfhi(unsigned int w) { return __uint_as_float(w & 0xffff0000u); }

// Repack W1[128][256] fp32 -> Wt[o][k] bf16, o in [0,256), k in [0,128)
// o <  128: Wt[o][k] = W1[o][k]           (A-part weights)
// o >= 128: Wt[o][k] = W1[o-128][128+k]   (B-part weights)
__global__ void build_wt(const float* __restrict__ W1, unsigned short* __restrict__ Wt) {
    int idx = blockIdx.x * 256 + threadIdx.x;   // 32768 total
    int o = idx >> 7, k = idx & 127;
    float v = (o < D) ? W1[o * TWO_D + k] : W1[(o - D) * TWO_D + D + k];
    Wt[idx] = f2bf(v);
}

// AB[n][o] = sum_k x[n][k] * Wt[o][k], stored bf16. Block = 256 thr = 4 waves;
// block handles 16 nodes x 256 outputs; wave w covers o in [64w, 64w+64).
__global__ __launch_bounds__(256) void gemm_nodes(
        const float* __restrict__ x, const unsigned short* __restrict__ Wt,
        unsigned short* __restrict__ AB) {
    const int wave = threadIdx.x >> 6;
    const int lane = threadIdx.x & 63;
    const int quad = lane >> 4;
    const int l16  = lane & 15;
    const int node_base = blockIdx.x << 4;
    const int node = node_base + l16;          // A-frag row: m = lane&15

    floatx4 acc[4];
#pragma unroll
    for (int t = 0; t < 4; ++t) acc[t] = (floatx4){0.f, 0.f, 0.f, 0.f};

#pragma unroll
    for (int ks = 0; ks < 4; ++ks) {
        const int kbase = ks * 32 + quad * 8;  // A layout: k = quad*8 + j
        const float* xp = x + node * D + kbase;
        floatx4 x0 = *(const floatx4*)xp;
        floatx4 x1 = *(const floatx4*)(xp + 4);
        short8 af;
        af[0] = (short)f2bf(x0[0]); af[1] = (short)f2bf(x0[1]);
        af[2] = (short)f2bf(x0[2]); af[3] = (short)f2bf(x0[3]);
        af[4] = (short)f2bf(x1[0]); af[5] = (short)f2bf(x1[1]);
        af[6] = (short)f2bf(x1[2]); af[7] = (short)f2bf(x1[3]);
#pragma unroll
        for (int t = 0; t < 4; ++t) {
            const int o = wave * 64 + t * 16 + l16;   // B layout: n = lane&15
            short8 bf = *(const short8*)(Wt + o * D + kbase);
            acc[t] = __builtin_amdgcn_mfma_f32_16x16x32_bf16(af, bf, acc[t], 0, 0, 0);
        }
    }
    // C/D layout: col = lane&15, row = quad*4 + reg
#pragma unroll
    for (int t = 0; t < 4; ++t) {
        const int o = wave * 64 + t * 16 + l16;
        const int mrow = node_base + quad * 4;
#pragma unroll
        for (int r = 0; r < 4; ++r) {
            AB[(mrow + r) * TWO_D + o] = f2bf(acc[t][r]);
        }
    }
}

// One 16-lane group per edge (grid-stride). Lane l handles h[j], j = 8l..8l+7.
__global__ __launch_bounds__(256) void edge_loss(
        const unsigned short* __restrict__ AB,
        const int* __restrict__ pairs,
        const float* __restrict__ labels,
        const float* __restrict__ b1,
        const float* __restrict__ W2,
        const float* __restrict__ b2,
        float* __restrict__ out, int E, float invE) {
    const int tid = threadIdx.x;
    const int l16 = tid & 15;
    const int grp = (blockIdx.x * blockDim.x + tid) >> 4;
    const int grpStride = (gridDim.x * blockDim.x) >> 4;
    const int jb = l16 * 8;

    // Per-lane constants (fixed j-range): registers, loaded once.
    float b1r[8], w2r[8];
#pragma unroll
    for (int j = 0; j < 8; ++j) { b1r[j] = b1[jb + j]; w2r[j] = W2[jb + j]; }
    const float bb2 = b2[0];

    float acc = 0.f;
    for (int e = grp; e < E; e += grpStride) {
        const int u = pairs[e];
        const int v = pairs[E + e];
        uint4 aw = *(const uint4*)(AB + u * TWO_D + jb);        // A[u][jb..jb+7]
        uint4 bw = *(const uint4*)(AB + v * TWO_D + D + jb);    // B[v][jb..jb+7]
        unsigned int wa[4] = {aw.x, aw.y, aw.z, aw.w};
        unsigned int wb[4] = {bw.x, bw.y, bw.z, bw.w};
        float partial = 0.f;
#pragma unroll
        for (int q = 0; q < 4; ++q) {
            float a0 = bflo(wa[q]), a1 = bfhi(wa[q]);
            float c0 = bflo(wb[q]), c1 = bfhi(wb[q]);
            float h0 = fmaxf(a0 + c0 + b1r[2 * q],     0.f);
            float h1 = fmaxf(a1 + c1 + b1r[2 * q + 1], 0.f);
            partial = fmaf(h0, w2r[2 * q],     partial);
            partial = fmaf(h1, w2r[2 * q + 1], partial);
        }
        // reduce across the 16-lane group
#pragma unroll
        for (int m = 8; m >= 1; m >>= 1) partial += __shfl_xor(partial, m, 16);
        if (l16 == 0) {
            float z = partial + bb2;
            float y = labels[e];
            // BCE-with-logits: softplus(z) - y*z (stable)
            float sp = fmaxf(z, 0.f) + log1pf(__expf(-fabsf(z)));
            acc += sp - y * z;
        }
    }

    // block reduction: wave shuffle -> LDS -> one atomic per block
#pragma unroll
    for (int m = 32; m >= 1; m >>= 1) acc += __shfl_down(acc, m, 64);
    __shared__ float red[4];
    const int wv = tid >> 6, ln = tid & 63;
    if (ln == 0) red[wv] = acc;
    __syncthreads();
    if (tid == 0) {
        float s = (red[0] + red[1]) + (red[2] + red[3]);
        atomicAdd(out, s * invE);
    }
}

extern "C" void kernel_launch(void* const* d_in, const int* in_sizes, int n_in,
                              void* d_out, int out_size, void* d_ws, size_t ws_size,
                              hipStream_t stream) {
    const float* x      = (const float*)d_in[0];
    const float* W1     = (const float*)d_in[1];
    const float* b1     = (const float*)d_in[2];
    const float* W2     = (const float*)d_in[3];
    const float* b2     = (const float*)d_in[4];
    const float* labels = (const float*)d_in[5];
    const int*   pairs  = (const int*)d_in[6];

    const int nNodes = in_sizes[0] / D;   // 50000
    const int E      = in_sizes[5];       // 600000

    unsigned short* Wt = (unsigned short*)d_ws;                        // 64 KiB
    unsigned short* AB = (unsigned short*)((char*)d_ws + 65536);       // nNodes*256*2 B

    hipMemsetAsync(d_out, 0, sizeof(float), stream);
    build_wt<<<128, 256, 0, stream>>>(W1, Wt);
    gemm_nodes<<<nNodes / 16, 256, 0, stream>>>(x, Wt, AB);
    edge_loss<<<2048, 256, 0, stream>>>(AB, pairs, labels, b1, W2, b2,
                                        (float*)d_out, E, 1.0f / (float)E);
}